// Round 8
// baseline (158.889 us; speedup 1.0000x reference)
//
#include <hip/hip_runtime.h>

// Problem constants (from reference): B,R,C,H,W = 4,2,19,256,512
constexpr int B = 4, R = 2, C = 19, H = 256, W = 512;
constexpr int HW = H * W;

// Output tile per block: 64 x 16 px; 256 threads, each thread = 4 consecutive x.
constexpr int BX = 64, BY = 16;
constexpr int NBX = W / BX;              // 8
constexpr int NBY = H / BY;              // 16
constexpr int NSPAT = B * NBX * NBY;     // 512 spatial tiles
// Channels split 10+9 across gridDim.y -> 1024 blocks.

// Staged pred tile: TW x TH per (buffer, ref). Halo: |mvx| < 12 px (6 sigma),
// |mvy| < 11 px (5.5 sigma) -- exceedances (P ~ 0.08 per full tensor) take the
// block-uniform global-gather fallback.
constexpr int TW = 88;                   // 12 + 64 + 11 + 1(pair)
constexpr int TH = 38;                   // 11 + 16 + 10 + 1(pair)
constexpr int TILE_N = TW * TH;          // 3344 floats = 13.4 KB
constexpr int TILE_V4 = TILE_N / 4;      // 836 float4 slots
constexpr int ROW_V4 = TW / 4;           // 22 float4 per tile row

// Async global->LDS DMA, 16B per lane. LDS dest = wave-uniform base + lane*16,
// which matches ldsoff = 16*(t + 256*i) exactly (contiguous in lane order).
__device__ __forceinline__ void dma16(const float* g, float* l) {
    __builtin_amdgcn_global_load_lds(
        (const __attribute__((address_space(1))) void*)g,
        (__attribute__((address_space(3))) void*)l, 16, 0, 0);
}

// R5/R6 lesson: NO register prefetch arrays (compiler sends them to scratch:
// WRITE_SIZE 39->330 MB). DMA staging keeps prefetch state out of VGPRs.
__global__ __launch_bounds__(256, 3) void mc_warp_kernel(
    const float* __restrict__ pred,   // [B,R,C,H,W]
    const float* __restrict__ mv,     // [B,R,2,H,W] quarter-pel
    const float* __restrict__ wgt,    // [B,R,1,H,W]
    float* __restrict__ out)          // [B,C,H,W]
{
    __shared__ float tiles[2][2][TILE_N];   // [buffer][ref][y*TW+x] = 53.5 KB

    int t = threadIdx.x;
    // XCD band swizzle: each XCD owns a contiguous (b, y-band).
    int xcd  = blockIdx.x & 7;
    int slot = blockIdx.x >> 3;
    int vblk = xcd * (NSPAT / 8) + slot;
    int bx   = vblk & (NBX - 1);
    int by   = (vblk >> 3) & (NBY - 1);
    int b    = vblk >> 7;
    int x0 = bx * BX, y0 = by * BY;
    int tx = t & 15, ty = t >> 4;
    int y  = y0 + ty;
    int xb = x0 + tx * 4;                 // first of this thread's 4 px

    // Tile origin, clamped fully inside the image (staging needs no clamps).
    int rowbase = min(max(y0 - 11, 0), H - TH);
    int colbase = min(max(x0 - 12, 0), W - TW);   // stays float4-aligned

    // Per-(ref, px) tap state: two row-pair offsets + 4 pair weights.
    int   off0[R][4], off1[R][4];
    int   offL0[R][4], offL1[R][4], offG0[R][4], offG1[R][4];
    float wq[R][4][4];
    int flag = 0;

    #pragma unroll
    for (int r = 0; r < R; ++r) {
        const float* mvp = mv + (size_t)((b * R + r) * 2) * HW + (size_t)y * W + xb;
        float4 mx4 = *(const float4*)(mvp);
        float4 my4 = *(const float4*)(mvp + HW);
        float4 wr4 = *(const float4*)(wgt + (size_t)(b * R + r) * HW + (size_t)y * W + xb);
        float mxs[4] = {mx4.x, mx4.y, mx4.z, mx4.w};
        float mys[4] = {my4.x, my4.y, my4.z, my4.w};
        float wrs[4] = {wr4.x, wr4.y, wr4.z, wr4.w};
        #pragma unroll
        for (int p = 0; p < 4; ++p) {
            int x = xb + p;
            float gx = (float)x + mxs[p] * 0.25f;   // quarter-pel -> pixel
            float gy = (float)y + mys[p] * 0.25f;
            float fx0 = floorf(gx), fy0 = floorf(gy);
            float wx1 = gx - fx0, wx0 = 1.0f - wx1;
            float wy1 = gy - fy0, wy0 = 1.0f - wy1;
            int ix0 = (int)fx0, iy0 = (int)fy0;
            int ix1 = ix0 + 1,  iy1 = iy0 + 1;

            // x pair: shift base into [0, W-2], route wx0/wx1 per element.
            int base = min(max(ix0, 0), W - 2);
            float wA = (ix0 == base)     ? wx0 : ((ix1 == base)     ? wx1 : 0.0f);
            float wB = (ix1 == base + 1) ? wx1 : ((ix0 == base + 1) ? wx0 : 0.0f);
            float wr = wrs[p];
            float wy0v = ((iy0 >= 0) && (iy0 < H)) ? wy0 * wr : 0.0f;
            float wy1v = ((iy1 >= 0) && (iy1 < H)) ? wy1 * wr : 0.0f;
            int cy0 = min(max(iy0, 0), H - 1);
            int cy1 = min(max(iy1, 0), H - 1);

            int l0 = base - colbase;
            int r0 = cy0 - rowbase, r1 = cy1 - rowbase;
            bool anyx = (wA != 0.0f) || (wB != 0.0f);
            bool anyy = (wy0v != 0.0f) || (wy1v != 0.0f);
            bool cb  = (l0 < 0 || l0 > TW - 2) && anyx && anyy;
            bool rb0 = (r0 < 0 || r0 > TH - 1) && (wy0v != 0.0f) && anyx;
            bool rb1 = (r1 < 0 || r1 > TH - 1) && (wy1v != 0.0f) && anyx;
            flag |= (int)(cb || rb0 || rb1);
            l0 = min(max(l0, 0), TW - 2);
            r0 = min(max(r0, 0), TH - 1);
            r1 = min(max(r1, 0), TH - 1);

            offL0[r][p] = r0 * TW + l0;
            offL1[r][p] = r1 * TW + l0;
            offG0[r][p] = cy0 * W + base;
            offG1[r][p] = cy1 * W + base;
            wq[r][p][0] = wy0v * wA;
            wq[r][p][1] = wy0v * wB;
            wq[r][p][2] = wy1v * wA;
            wq[r][p][3] = wy1v * wB;
        }
    }

    // Block-uniform fallback: any tap outside the halo -> global gathers.
    int fbB = __syncthreads_or(flag);
    #pragma unroll
    for (int r = 0; r < R; ++r)
        #pragma unroll
        for (int p = 0; p < 4; ++p) {
            off0[r][p] = fbB ? offG0[r][p] : offL0[r][p];
            off1[r][p] = fbB ? offG1[r][p] : offL1[r][p];
        }

    // Staging slots: thread t, slot i covers float4 #(t+256i) of the tile.
    int sgoff[4], smask[4], ldsoff[4];
    #pragma unroll
    for (int i = 0; i < 4; ++i) {
        int idx = t + 256 * i;
        smask[i]  = idx < TILE_V4;
        int row = idx / ROW_V4;
        int col = (idx - row * ROW_V4) * 4;
        sgoff[i]  = row * W + col;            // global offset within staged window
        ldsoff[i] = 4 * idx;                  // contiguous LDS float offset
    }

    const float* pl0 = pred + (size_t)(b * R + 0) * C * HW;
    const float* pl1 = pred + (size_t)(b * R + 1) * C * HW;
    const float* st0 = pl0 + (size_t)rowbase * W + colbase;
    const float* st1 = pl1 + (size_t)rowbase * W + colbase;
    float* ob = out + (size_t)b * C * HW + (size_t)y * W + xb;

    int cbeg = (blockIdx.y == 0) ? 0 : 10;
    int cend = (blockIdx.y == 0) ? 10 : 19;

    // Prologue: DMA channel cbeg into buffer 0.
    if (!fbB) {
        const float* s0 = st0 + (size_t)cbeg * HW;
        const float* s1 = st1 + (size_t)cbeg * HW;
        #pragma unroll
        for (int i = 0; i < 4; ++i) if (smask[i]) {
            dma16(s0 + sgoff[i], &tiles[0][0][ldsoff[i]]);
            dma16(s1 + sgoff[i], &tiles[0][1][ldsoff[i]]);
        }
    }

    int cur = 0;
    for (int c = cbeg; c < cend; ++c) {
        float res[4];
        if (!fbB) {
            // Drains this wave's DMA (compiler emits vmcnt(0) before s_barrier)
            // and all waves' prior-round LDS tap reads of the buffer we're
            // about to overwrite.
            __syncthreads();
            if (c + 1 < cend) {
                const float* s0 = st0 + (size_t)(c + 1) * HW;
                const float* s1 = st1 + (size_t)(c + 1) * HW;
                int nb = cur ^ 1;
                #pragma unroll
                for (int i = 0; i < 4; ++i) if (smask[i]) {
                    dma16(s0 + sgoff[i], &tiles[nb][0][ldsoff[i]]);
                    dma16(s1 + sgoff[i], &tiles[nb][1][ldsoff[i]]);
                }
            }
            const float* t0 = tiles[cur][0];
            const float* t1 = tiles[cur][1];
            #pragma unroll
            for (int p = 0; p < 4; ++p) {
                float a00 = t0[off0[0][p]], a01 = t0[off0[0][p] + 1];
                float a10 = t0[off1[0][p]], a11 = t0[off1[0][p] + 1];
                float b00 = t1[off0[1][p]], b01 = t1[off0[1][p] + 1];
                float b10 = t1[off1[1][p]], b11 = t1[off1[1][p] + 1];
                res[p] = wq[0][p][0] * a00 + wq[0][p][1] * a01
                       + wq[0][p][2] * a10 + wq[0][p][3] * a11
                       + wq[1][p][0] * b00 + wq[1][p][1] * b01
                       + wq[1][p][2] * b10 + wq[1][p][3] * b11;
            }
            cur ^= 1;
        } else {
            const float* pc0 = pl0 + (size_t)c * HW;
            const float* pc1 = pl1 + (size_t)c * HW;
            #pragma unroll
            for (int p = 0; p < 4; ++p) {
                float a00 = pc0[off0[0][p]], a01 = pc0[off0[0][p] + 1];
                float a10 = pc0[off1[0][p]], a11 = pc0[off1[0][p] + 1];
                float b00 = pc1[off0[1][p]], b01 = pc1[off0[1][p] + 1];
                float b10 = pc1[off1[1][p]], b11 = pc1[off1[1][p] + 1];
                res[p] = wq[0][p][0] * a00 + wq[0][p][1] * a01
                       + wq[0][p][2] * a10 + wq[0][p][3] * a11
                       + wq[1][p][0] * b00 + wq[1][p][1] * b01
                       + wq[1][p][2] * b10 + wq[1][p][3] * b11;
            }
        }
        *(float4*)(ob + (size_t)c * HW) = make_float4(res[0], res[1], res[2], res[3]);
    }
}

extern "C" void kernel_launch(void* const* d_in, const int* in_sizes, int n_in,
                              void* d_out, int out_size, void* d_ws, size_t ws_size,
                              hipStream_t stream) {
    const float* pred = (const float*)d_in[0];   // [B,R,C,H,W] fp32
    const float* mv   = (const float*)d_in[1];   // [B,R,2,H,W] fp32
    const float* wgt  = (const float*)d_in[2];   // [B,R,1,H,W] fp32
    float* out = (float*)d_out;                  // [B,C,H,W] fp32

    dim3 grid(NSPAT, 2);                         // 512 spatial tiles x 2 channel chunks
    mc_warp_kernel<<<grid, dim3(256), 0, stream>>>(pred, mv, wgt, out);
}